// Round 9
// baseline (134.439 us; speedup 1.0000x reference)
//
#include <hip/hip_runtime.h>

// HMM forward: alpha_t = (alpha_{t-1} @ A) * B[:, obs[t]]; out[t][s] = alpha_t[s].
// S=2048, T=8192, 512 symbols, fp32.
//
// alpha decays ~512x/step -> exact-zero underflow at t~17; after the first
// all-zero row every later row is zero (verified R1-R8, absmax 1e-38).
// Honest recurrence + all-zero detection + tail zero-fill.
//
// R8 post-mortem: 57us = ~35 steps + ~3 hoist + ~3 decode/rendezvous + ~15-20
// fill (64 CUs storing 67MB: CU-rate-bound). R9:
//  - comm ring moves to d_ws (depth 2 x 2048 enc floats). Epoch-alternating
//    bias: row t -> slot t&1, bias (t>>1)&1 ? 0xC0000000 : 0x40000000. Stale
//    slot data (row t-2) has the OTHER bias -> not-ready; poison 0xAA.. is in
//    neither range -> not-ready. out gets PLAIN stores (off critical path) ->
//    no decode pass, no post-loop rendezvous, no d_ws memset.
//  - 256 blocks: 0-63 run the recurrence (R8-verified structure: register-
//    resident A, 16-scalar batch poll, ONE barrier/step); 64-255 spin on a
//    'stop' word (published the moment termination is detected) then ALL 256
//    blocks zero-fill the tail -> 4x fill CUs + earlier start.
// Fully data-dependent: would honestly run all 8191 steps if no underflow.

#define S     2048
#define T     8192
#define NSYM  512
#define NRBLK 64           // recurrence blocks
#define NBLK  256          // total blocks
#define NTHR  1024

typedef int v4i __attribute__((ext_vector_type(4)));

__device__ __forceinline__ void store_coherent_i4(int* p, v4i v) {
    asm volatile("global_store_dwordx4 %0, %1, off sc0 sc1"
                 :: "v"(p), "v"(v) : "memory");
}

// 4 coherent scalar loads from one base (+0,+32,+64,+96 bytes), NO waitcnt.
#define POLL4(e0,e1,e2,e3,bp)                                              \
    asm volatile("global_load_dword %0, %4, off sc0 sc1\n\t"               \
                 "global_load_dword %1, %4, off offset:32 sc0 sc1\n\t"     \
                 "global_load_dword %2, %4, off offset:64 sc0 sc1\n\t"     \
                 "global_load_dword %3, %4, off offset:96 sc0 sc1"         \
                 : "=&v"(e0), "=&v"(e1), "=&v"(e2), "=&v"(e3)              \
                 : "v"(bp) : "memory")

__global__ void __launch_bounds__(NTHR) hmm_fwd(
    const int*   __restrict__ obs,
    const float* __restrict__ A,
    const float* __restrict__ B,
    const float* __restrict__ pi,
    float*       __restrict__ out,
    int*         __restrict__ ring,    // d_ws: int ring[2][S]; int stop;
    int*         __restrict__ stop)
{
    __shared__ float4 s_wpart[16][8];  // 2 KB per-wave partials
    __shared__ int    s_nz[4];         // depth-4 parity "row nonzero"
    __shared__ int    s_stop;

    const int tx = threadIdx.x;
    const int b  = blockIdx.x;

    int firstZero;                     // first all-zero row index (== T if none)

    if (b < NRBLK) {
        // ================= recurrence path (R8-verified structure) =========
        const int lane = tx & 63;
        const int w    = tx >> 6;      // wave id 0..15
        const int jl4  = lane & 7;     // col float4 within block (0..7)
        const int r_l  = lane >> 3;    // row-within-group (0..7)
        const int col4 = b * 8 + jl4;
        const float4* A4 = (const float4*)A;

        // block's A slice, step-invariant, register-resident
        float4 a_reg[4][4];
        #pragma unroll
        for (int q = 0; q < 4; ++q)
            #pragma unroll
            for (int s = 0; s < 4; ++s) {
                const int i = (w + 16 * q) * 32 + s * 8 + r_l;
                a_reg[q][s] = A4[(size_t)i * (S / 4) + col4];
            }

        // ---- step 0: publish encoded alpha0 (bias A) + plain out row 0 ----
        if (tx < 8) {
            const int o0 = obs[0];
            const int j  = b * 32 + tx * 4;
            float4 r;
            r.x = pi[j + 0] * B[(size_t)(j + 0) * NSYM + o0];
            r.y = pi[j + 1] * B[(size_t)(j + 1) * NSYM + o0];
            r.z = pi[j + 2] * B[(size_t)(j + 2) * NSYM + o0];
            r.w = pi[j + 3] * B[(size_t)(j + 3) * NSYM + o0];
            v4i e;
            e.x = (int)((unsigned)__float_as_int(r.x) + 0x40000000u);
            e.y = (int)((unsigned)__float_as_int(r.y) + 0x40000000u);
            e.z = (int)((unsigned)__float_as_int(r.z) + 0x40000000u);
            e.w = (int)((unsigned)__float_as_int(r.w) + 0x40000000u);
            store_coherent_i4(ring + j, e);
            ((float4*)out)[b * 8 + tx] = r;       // plain, off critical path
        }
        if (tx == 0) { s_nz[0] = 0; s_nz[1] = 0; s_nz[2] = 0; s_nz[3] = 0; }
        __syncthreads();

        int lastRow = T - 1;

        for (int t = 1; t < T; ++t) {
            // emission prefetch (wave0 lanes; same lanes publish later)
            float em0 = 0.f, em1 = 0.f, em2 = 0.f, em3 = 0.f;
            if (tx < 8) {
                const int o = obs[t];
                const int j = b * 32 + tx * 4;
                em0 = B[(size_t)(j + 0) * NSYM + o];
                em1 = B[(size_t)(j + 1) * NSYM + o];
                em2 = B[(size_t)(j + 2) * NSYM + o];
                em3 = B[(size_t)(j + 3) * NSYM + o];
            }

            // batch-poll this wave's 16 encoded alpha scalars of row t-1
            const unsigned bp = (((t - 1) >> 1) & 1) ? 0xC0000000u : 0x40000000u;
            const int* rb = ring + ((t - 1) & 1) * S + r_l;
            const int* b0 = rb + (w +  0) * 32;
            const int* b1 = rb + (w + 16) * 32;
            const int* b2 = rb + (w + 32) * 32;
            const int* b3 = rb + (w + 48) * 32;
            int e00, e01, e02, e03, e10, e11, e12, e13;
            int e20, e21, e22, e23, e30, e31, e32, e33;
            #define RDY(E) ((unsigned)((unsigned)(E) - bp) <= 0x3F800000u)
            for (;;) {
                POLL4(e00, e01, e02, e03, b0);
                POLL4(e10, e11, e12, e13, b1);
                POLL4(e20, e21, e22, e23, b2);
                POLL4(e30, e31, e32, e33, b3);
                asm volatile("s_waitcnt vmcnt(0)" ::: "memory");
                if (RDY(e00) && RDY(e01) && RDY(e02) && RDY(e03) &&
                    RDY(e10) && RDY(e11) && RDY(e12) && RDY(e13) &&
                    RDY(e20) && RDY(e21) && RDY(e22) && RDY(e23) &&
                    RDY(e30) && RDY(e31) && RDY(e32) && RDY(e33)) break;
            }
            #undef RDY

            // decode + FMA vs register-resident A
            float4 acc = make_float4(0.f, 0.f, 0.f, 0.f);
            int nzacc = 0;
            #define STEP1(E, Q, Ss)                                            \
                { const int d = (int)((unsigned)(E) - bp); nzacc |= d;         \
                  const float af = __int_as_float(d);                          \
                  acc.x = fmaf(af, a_reg[Q][Ss].x, acc.x);                     \
                  acc.y = fmaf(af, a_reg[Q][Ss].y, acc.y);                     \
                  acc.z = fmaf(af, a_reg[Q][Ss].z, acc.z);                     \
                  acc.w = fmaf(af, a_reg[Q][Ss].w, acc.w); }
            STEP1(e00,0,0) STEP1(e01,0,1) STEP1(e02,0,2) STEP1(e03,0,3)
            STEP1(e10,1,0) STEP1(e11,1,1) STEP1(e12,1,2) STEP1(e13,1,3)
            STEP1(e20,2,0) STEP1(e21,2,1) STEP1(e22,2,2) STEP1(e23,2,3)
            STEP1(e30,3,0) STEP1(e31,3,1) STEP1(e32,3,2) STEP1(e33,3,3)
            #undef STEP1

            // in-wave reduce over lane bits 3,4,5 (the 8 r_l groups)
            #pragma unroll
            for (int m = 8; m <= 32; m <<= 1) {
                acc.x += __shfl_xor(acc.x, m);
                acc.y += __shfl_xor(acc.y, m);
                acc.z += __shfl_xor(acc.z, m);
                acc.w += __shfl_xor(acc.w, m);
            }
            if (lane < 8) s_wpart[w][lane] = acc;
            const unsigned long long nzm = __ballot(nzacc != 0);
            if (nzm != 0ull && lane == 0) s_nz[t & 3] = 1;  // benign same-value race
            if (tx == 0) s_nz[(t + 2) & 3] = 0;             // prep 2 steps ahead
            __syncthreads();                                // the ONLY per-step barrier

            if (s_nz[t & 3] == 0) { lastRow = t - 1; break; }

            // wave0: combine 16 wave-partials, emission-multiply, publish
            if (tx < 64) {
                const int h = tx >> 3, c = tx & 7;
                float4 p = s_wpart[h][c];
                const float4 q4 = s_wpart[h + 8][c];
                p.x += q4.x; p.y += q4.y; p.z += q4.z; p.w += q4.w;
                #pragma unroll
                for (int m = 8; m <= 32; m <<= 1) {
                    p.x += __shfl_xor(p.x, m);
                    p.y += __shfl_xor(p.y, m);
                    p.z += __shfl_xor(p.z, m);
                    p.w += __shfl_xor(p.w, m);
                }
                if (tx < 8) {
                    float4 r;
                    r.x = p.x * em0; r.y = p.y * em1;
                    r.z = p.z * em2; r.w = p.w * em3;
                    const unsigned bt = ((t >> 1) & 1) ? 0xC0000000u : 0x40000000u;
                    v4i e;
                    e.x = (int)((unsigned)__float_as_int(r.x) + bt);
                    e.y = (int)((unsigned)__float_as_int(r.y) + bt);
                    e.z = (int)((unsigned)__float_as_int(r.z) + bt);
                    e.w = (int)((unsigned)__float_as_int(r.w) + bt);
                    store_coherent_i4(ring + (t & 1) * S + b * 32 + tx * 4, e);
                    ((float4*)(out + (size_t)t * S))[b * 8 + tx] = r;  // plain
                }
            }
            // no bottom barrier: next step's polls gate progress (R8-verified)
        }

        firstZero = lastRow + 1;
        // publish stop ASAP so fill blocks start immediately
        if (tx == 0)
            asm volatile("global_store_dword %0, %1, off sc0 sc1"
                         :: "v"(stop), "v"(firstZero) : "memory");
    } else {
        // ================= fill-helper path ================================
        if (tx == 0) {
            int v;
            for (;;) {
                asm volatile("global_load_dword %0, %1, off sc0 sc1\n\t"
                             "s_waitcnt vmcnt(0)"
                             : "=v"(v) : "v"(stop) : "memory");
                if ((unsigned)(v - 1) < (unsigned)T) break;   // v in [1,T]; poison fails
                __builtin_amdgcn_s_sleep(8);
            }
            s_stop = v;
        }
        __syncthreads();
        firstZero = s_stop;
    }

    // ---- tail zero-fill: rows firstZero .. T-1, all 256 blocks ----
    {
        const size_t beg4 = (size_t)firstZero * (S / 4);
        const size_t end4 = (size_t)T * (S / 4);
        const float4 z = make_float4(0.f, 0.f, 0.f, 0.f);
        float4* o4 = (float4*)out;
        for (size_t i = beg4 + (size_t)b * NTHR + tx; i < end4;
             i += (size_t)NBLK * NTHR)
            o4[i] = z;
    }
}

extern "C" void kernel_launch(void* const* d_in, const int* in_sizes, int n_in,
                              void* d_out, int out_size, void* d_ws, size_t ws_size,
                              hipStream_t stream) {
    const int*   obs = (const int*)d_in[0];
    const float* A   = (const float*)d_in[1];
    const float* B   = (const float*)d_in[2];
    const float* pi  = (const float*)d_in[3];
    float* out = (float*)d_out;
    int* ring = (int*)d_ws;            // 2*S ints = 16 KB
    int* stop = ring + 2 * S;

    // No memset needed: ring not-ready relies on epoch bias (poison 0xAA.. is
    // outside both bias ranges); stop readiness is a range check.
    hmm_fwd<<<dim3(NBLK), dim3(NTHR), 0, stream>>>(obs, A, B, pi, out, ring, stop);
}

// Round 10
// 134.010 us; speedup vs baseline: 1.0032x; 1.0032x over previous
//
#include <hip/hip_runtime.h>

// HMM forward: alpha_t = (alpha_{t-1} @ A) * B[:, obs[t]]; out[t][s] = alpha_t[s].
// S=2048, T=8192, 512 symbols, fp32.
//
// alpha decays ~512x/step -> exact-zero underflow at t~17; after the first
// all-zero row every later row is zero (verified R1-R9, absmax 1e-38).
//
// R9 post-mortem: tail fill (66MB) is HBM-write-bound ~17us regardless of CU
// count. R10: fill rows 64..T-1 SPECULATIVELY, concurrent with the recurrence:
//  - filler blocks (64..255) zero rows >=64 immediately via sc0/sc1 stores
//    (bypass XCD L2 -> cannot evict the L2-resident A slices), raise per-block
//    magic done-flags, then wait for stop and help with the residual.
//  - recurrence blocks rendezvous on the done-flags IF they ever reach t=64
//    (never happens with underflowing data; proves fill-before-overwrite
//    ordering in the no-underflow world) -> race-free in all cases.
//  - after termination only rows [firstZero,64) remain: ~376KB, instant.
// Recurrence structure unchanged from R8/R9 (register-resident A, 16-scalar
// batch poll of the d_ws ring with epoch-alternating bias, ONE barrier/step).
// Fully data-dependent: would honestly run all 8191 steps if no underflow.

#define S     2048
#define T     8192
#define NSYM  512
#define NRBLK 64           // recurrence blocks
#define NBLK  256          // total blocks
#define NFILL (NBLK - NRBLK)
#define NTHR  1024
#define MAGIC 0x600DF00D   // != 0xAAAAAAAA poison

typedef int v4i __attribute__((ext_vector_type(4)));

__device__ __forceinline__ void store_coherent_i4(int* p, v4i v) {
    asm volatile("global_store_dwordx4 %0, %1, off sc0 sc1"
                 :: "v"(p), "v"(v) : "memory");
}

// 4 coherent scalar loads from one base (+0,+32,+64,+96 bytes), NO waitcnt.
#define POLL4(e0,e1,e2,e3,bp)                                              \
    asm volatile("global_load_dword %0, %4, off sc0 sc1\n\t"               \
                 "global_load_dword %1, %4, off offset:32 sc0 sc1\n\t"     \
                 "global_load_dword %2, %4, off offset:64 sc0 sc1\n\t"     \
                 "global_load_dword %3, %4, off offset:96 sc0 sc1"         \
                 : "=&v"(e0), "=&v"(e1), "=&v"(e2), "=&v"(e3)              \
                 : "v"(bp) : "memory")

__global__ void __launch_bounds__(NTHR) hmm_fwd(
    const int*   __restrict__ obs,
    const float* __restrict__ A,
    const float* __restrict__ B,
    const float* __restrict__ pi,
    float*       __restrict__ out,
    int*         __restrict__ ring,    // d_ws: int ring[2][S]; int stop; int doneF[192];
    int*         __restrict__ stop,
    int*         __restrict__ doneF)
{
    __shared__ float4 s_wpart[16][8];  // 2 KB per-wave partials
    __shared__ int    s_nz[4];         // depth-4 parity "row nonzero"
    __shared__ int    s_stop;

    const int tx = threadIdx.x;
    const int b  = blockIdx.x;

    int firstZero;                     // first all-zero row index (== T if none)

    if (b < NRBLK) {
        // ================= recurrence path (R8/R9-verified) ================
        const int lane = tx & 63;
        const int w    = tx >> 6;      // wave id 0..15
        const int jl4  = lane & 7;     // col float4 within block (0..7)
        const int r_l  = lane >> 3;    // row-within-group (0..7)
        const int col4 = b * 8 + jl4;
        const float4* A4 = (const float4*)A;

        // block's A slice, step-invariant, register-resident
        float4 a_reg[4][4];
        #pragma unroll
        for (int q = 0; q < 4; ++q)
            #pragma unroll
            for (int s = 0; s < 4; ++s) {
                const int i = (w + 16 * q) * 32 + s * 8 + r_l;
                a_reg[q][s] = A4[(size_t)i * (S / 4) + col4];
            }

        // ---- step 0: publish encoded alpha0 (bias A) + plain out row 0 ----
        if (tx < 8) {
            const int o0 = obs[0];
            const int j  = b * 32 + tx * 4;
            float4 r;
            r.x = pi[j + 0] * B[(size_t)(j + 0) * NSYM + o0];
            r.y = pi[j + 1] * B[(size_t)(j + 1) * NSYM + o0];
            r.z = pi[j + 2] * B[(size_t)(j + 2) * NSYM + o0];
            r.w = pi[j + 3] * B[(size_t)(j + 3) * NSYM + o0];
            v4i e;
            e.x = (int)((unsigned)__float_as_int(r.x) + 0x40000000u);
            e.y = (int)((unsigned)__float_as_int(r.y) + 0x40000000u);
            e.z = (int)((unsigned)__float_as_int(r.z) + 0x40000000u);
            e.w = (int)((unsigned)__float_as_int(r.w) + 0x40000000u);
            store_coherent_i4(ring + j, e);
            ((float4*)out)[b * 8 + tx] = r;       // plain, off critical path
        }
        if (tx == 0) { s_nz[0] = 0; s_nz[1] = 0; s_nz[2] = 0; s_nz[3] = 0; }
        __syncthreads();

        int lastRow = T - 1;

        for (int t = 1; t < T; ++t) {
            // no-underflow guard: before touching row 64, wait for the
            // speculative fill to finish (proves fill-store < our-store on
            // rows >= 64). Never taken with underflowing data.
            if (t == 64) {
                if (tx < NFILL) {       // waves 0..2, 64 flags each
                    for (;;) {
                        int v;
                        asm volatile("global_load_dword %0, %1, off sc0 sc1\n\t"
                                     "s_waitcnt vmcnt(0)"
                                     : "=v"(v) : "v"(doneF + tx) : "memory");
                        if (__all(v == MAGIC)) break;
                        __builtin_amdgcn_s_sleep(8);
                    }
                }
                __syncthreads();
            }

            // emission prefetch (wave0 lanes; same lanes publish later)
            float em0 = 0.f, em1 = 0.f, em2 = 0.f, em3 = 0.f;
            if (tx < 8) {
                const int o = obs[t];
                const int j = b * 32 + tx * 4;
                em0 = B[(size_t)(j + 0) * NSYM + o];
                em1 = B[(size_t)(j + 1) * NSYM + o];
                em2 = B[(size_t)(j + 2) * NSYM + o];
                em3 = B[(size_t)(j + 3) * NSYM + o];
            }

            // batch-poll this wave's 16 encoded alpha scalars of row t-1
            const unsigned bp = (((t - 1) >> 1) & 1) ? 0xC0000000u : 0x40000000u;
            const int* rb = ring + ((t - 1) & 1) * S + r_l;
            const int* b0 = rb + (w +  0) * 32;
            const int* b1 = rb + (w + 16) * 32;
            const int* b2 = rb + (w + 32) * 32;
            const int* b3 = rb + (w + 48) * 32;
            int e00, e01, e02, e03, e10, e11, e12, e13;
            int e20, e21, e22, e23, e30, e31, e32, e33;
            #define RDY(E) ((unsigned)((unsigned)(E) - bp) <= 0x3F800000u)
            for (;;) {
                POLL4(e00, e01, e02, e03, b0);
                POLL4(e10, e11, e12, e13, b1);
                POLL4(e20, e21, e22, e23, b2);
                POLL4(e30, e31, e32, e33, b3);
                asm volatile("s_waitcnt vmcnt(0)" ::: "memory");
                if (RDY(e00) && RDY(e01) && RDY(e02) && RDY(e03) &&
                    RDY(e10) && RDY(e11) && RDY(e12) && RDY(e13) &&
                    RDY(e20) && RDY(e21) && RDY(e22) && RDY(e23) &&
                    RDY(e30) && RDY(e31) && RDY(e32) && RDY(e33)) break;
            }
            #undef RDY

            // decode + FMA vs register-resident A
            float4 acc = make_float4(0.f, 0.f, 0.f, 0.f);
            int nzacc = 0;
            #define STEP1(E, Q, Ss)                                            \
                { const int d = (int)((unsigned)(E) - bp); nzacc |= d;         \
                  const float af = __int_as_float(d);                          \
                  acc.x = fmaf(af, a_reg[Q][Ss].x, acc.x);                     \
                  acc.y = fmaf(af, a_reg[Q][Ss].y, acc.y);                     \
                  acc.z = fmaf(af, a_reg[Q][Ss].z, acc.z);                     \
                  acc.w = fmaf(af, a_reg[Q][Ss].w, acc.w); }
            STEP1(e00,0,0) STEP1(e01,0,1) STEP1(e02,0,2) STEP1(e03,0,3)
            STEP1(e10,1,0) STEP1(e11,1,1) STEP1(e12,1,2) STEP1(e13,1,3)
            STEP1(e20,2,0) STEP1(e21,2,1) STEP1(e22,2,2) STEP1(e23,2,3)
            STEP1(e30,3,0) STEP1(e31,3,1) STEP1(e32,3,2) STEP1(e33,3,3)
            #undef STEP1

            // in-wave reduce over lane bits 3,4,5 (the 8 r_l groups)
            #pragma unroll
            for (int m = 8; m <= 32; m <<= 1) {
                acc.x += __shfl_xor(acc.x, m);
                acc.y += __shfl_xor(acc.y, m);
                acc.z += __shfl_xor(acc.z, m);
                acc.w += __shfl_xor(acc.w, m);
            }
            if (lane < 8) s_wpart[w][lane] = acc;
            const unsigned long long nzm = __ballot(nzacc != 0);
            if (nzm != 0ull && lane == 0) s_nz[t & 3] = 1;  // benign same-value race
            if (tx == 0) s_nz[(t + 2) & 3] = 0;             // prep 2 steps ahead
            __syncthreads();                                // the ONLY per-step barrier

            if (s_nz[t & 3] == 0) { lastRow = t - 1; break; }

            // wave0: combine 16 wave-partials, emission-multiply, publish
            if (tx < 64) {
                const int h = tx >> 3, c = tx & 7;
                float4 p = s_wpart[h][c];
                const float4 q4 = s_wpart[h + 8][c];
                p.x += q4.x; p.y += q4.y; p.z += q4.z; p.w += q4.w;
                #pragma unroll
                for (int m = 8; m <= 32; m <<= 1) {
                    p.x += __shfl_xor(p.x, m);
                    p.y += __shfl_xor(p.y, m);
                    p.z += __shfl_xor(p.z, m);
                    p.w += __shfl_xor(p.w, m);
                }
                if (tx < 8) {
                    float4 r;
                    r.x = p.x * em0; r.y = p.y * em1;
                    r.z = p.z * em2; r.w = p.w * em3;
                    const unsigned bt = ((t >> 1) & 1) ? 0xC0000000u : 0x40000000u;
                    v4i e;
                    e.x = (int)((unsigned)__float_as_int(r.x) + bt);
                    e.y = (int)((unsigned)__float_as_int(r.y) + bt);
                    e.z = (int)((unsigned)__float_as_int(r.z) + bt);
                    e.w = (int)((unsigned)__float_as_int(r.w) + bt);
                    store_coherent_i4(ring + (t & 1) * S + b * 32 + tx * 4, e);
                    ((float4*)(out + (size_t)t * S))[b * 8 + tx] = r;  // plain
                }
            }
            // no bottom barrier: next step's polls gate progress (R8-verified)
        }

        firstZero = lastRow + 1;
        // publish stop ASAP (64 same-value sc1 stores: benign)
        if (tx == 0)
            asm volatile("global_store_dword %0, %1, off sc0 sc1"
                         :: "v"(stop), "v"(firstZero) : "memory");
    } else {
        // ================= speculative-fill path ===========================
        // zero rows 64..T-1 NOW, via sc0/sc1 (bypasses XCD L2 -> A untouched)
        {
            const size_t beg4 = (size_t)64 * (S / 4);
            const size_t end4 = (size_t)T * (S / 4);
            const v4i z = { 0, 0, 0, 0 };
            int* o4 = (int*)out;
            for (size_t i = beg4 + (size_t)(b - NRBLK) * NTHR + tx; i < end4;
                 i += (size_t)NFILL * NTHR)
                store_coherent_i4(o4 + i * 4, z);
            asm volatile("s_waitcnt vmcnt(0)" ::: "memory");
        }
        __syncthreads();
        if (tx == 0) {
            const int m = MAGIC;
            asm volatile("global_store_dword %0, %1, off sc0 sc1"
                         :: "v"(doneF + (b - NRBLK)), "v"(m) : "memory");
        }

        // wait for termination
        if (tx == 0) {
            int v;
            for (;;) {
                asm volatile("global_load_dword %0, %1, off sc0 sc1\n\t"
                             "s_waitcnt vmcnt(0)"
                             : "=v"(v) : "v"(stop) : "memory");
                if ((unsigned)(v - 1) < (unsigned)T) break;  // v in [1,T]; poison fails
                __builtin_amdgcn_s_sleep(8);
            }
            s_stop = v;
        }
        __syncthreads();
        firstZero = s_stop;
    }

    // ---- residual fill: rows firstZero..63 (empty if firstZero >= 64) ----
    {
        const size_t beg4 = (size_t)firstZero * (S / 4);
        const size_t end4 = (size_t)64 * (S / 4);
        const float4 z = make_float4(0.f, 0.f, 0.f, 0.f);
        float4* o4 = (float4*)out;
        for (size_t i = beg4 + (size_t)b * NTHR + tx; i < end4;
             i += (size_t)NBLK * NTHR)
            o4[i] = z;
    }
}

extern "C" void kernel_launch(void* const* d_in, const int* in_sizes, int n_in,
                              void* d_out, int out_size, void* d_ws, size_t ws_size,
                              hipStream_t stream) {
    const int*   obs = (const int*)d_in[0];
    const float* A   = (const float*)d_in[1];
    const float* B   = (const float*)d_in[2];
    const float* pi  = (const float*)d_in[3];
    float* out = (float*)d_out;
    int* ring  = (int*)d_ws;           // 2*S ints = 16 KB
    int* stop  = ring + 2 * S;
    int* doneF = stop + 1;             // 192 ints

    // No memset needed: ring readiness = epoch bias; stop = range check;
    // doneF = magic check. Harness re-poisons d_ws to 0xAA each launch.
    hmm_fwd<<<dim3(NBLK), dim3(NTHR), 0, stream>>>(obs, A, B, pi, out,
                                                   ring, stop, doneF);
}